// Round 1
// baseline (1354.913 us; speedup 1.0000x reference)
//
#include <hip/hip_runtime.h>

#define DD 128
#define TM 128
#define LDW 136  // 128 + 8 ushort pad: breaks power-of-2 LDS row stride

typedef __attribute__((ext_vector_type(8))) short frag8;       // 8 bf16 (4 VGPRs)
typedef __attribute__((ext_vector_type(4))) float f32x4;       // MFMA C/D
typedef __attribute__((ext_vector_type(4))) unsigned short us4;

__device__ __forceinline__ unsigned short f2bf(float f) {
  union { float f; unsigned u; } x; x.f = f;
  unsigned r = x.u + 0x7fffu + ((x.u >> 16) & 1u);  // RNE
  return (unsigned short)(r >> 16);
}
__device__ __forceinline__ float bf2f(unsigned short h) {
  union { unsigned u; float f; } x; x.u = ((unsigned)h) << 16;
  return x.f;
}
__device__ __forceinline__ void store4bf(unsigned short* p, float4 f) {
  us4 v;
  v.x = f2bf(f.x); v.y = f2bf(f.y); v.z = f2bf(f.z); v.w = f2bf(f.w);
  *reinterpret_cast<us4*>(p) = v;  // 8B ds_write
}

// ---- K_w: convert all four weight matrices fp32 -> bf16 into workspace ----
// layout (ushort offsets): W1 @0 (16384), W2 @16384, W_ih @32768 (49152), W_hh @81920 (49152)
__global__ __launch_bounds__(256) void convert_weights(
    const float* __restrict__ W1, const float* __restrict__ W2,
    const float* __restrict__ Wih, const float* __restrict__ Whh,
    unsigned short* __restrict__ dst) {
  int i = blockIdx.x * 256 + threadIdx.x;
  if (i >= 131072) return;
  float v;
  if (i < 16384)      v = W1[i];
  else if (i < 32768) v = W2[i - 16384];
  else if (i < 81920) v = Wih[i - 32768];
  else                v = Whh[i - 81920];
  dst[i] = f2bf(v);
}

// ---- K0: winner[i] = -1 ----
__global__ __launch_bounds__(256) void init_winner(int* __restrict__ w, int N) {
  int i = blockIdx.x * 256 + threadIdx.x;
  if (i < N) w[i] = -1;
}

// ---- K1: winner[idx[b]] = max b  (numpy last-occurrence-wins semantics) ----
__global__ __launch_bounds__(256) void scatter_winner(
    const int* __restrict__ idx, int* __restrict__ w, int B) {
  int b = blockIdx.x * 256 + threadIdx.x;
  if (b < B) atomicMax(w + idx[b], b);
}

// ---- K2: fused MLP (Linear-ELU-Linear) + gather mem + GRUCell ----
// block = 256 threads = 4 waves; tile = 128 rows; each wave owns 32 rows.
// Chained bf16 MFMA GEMMs through LDS; weights (bf16, L2-resident) feed B-frags
// directly from global: frag = 8 contiguous bf16 along K = one 16B load.
__global__ __launch_bounds__(256, 2) void mlp_gru(
    const float* __restrict__ x, const int* __restrict__ idx,
    const float* __restrict__ hist, const unsigned short* __restrict__ wbf,
    const float* __restrict__ b1, const float* __restrict__ b2,
    const float* __restrict__ bih, const float* __restrict__ bhh,
    float* __restrict__ out, float* __restrict__ memo, long long N) {
  __shared__ __align__(16) unsigned short sA[TM * LDW];  // X, then xf
  __shared__ __align__(16) unsigned short sB[TM * LDW];  // h1, then mem
  const int t = threadIdx.x;
  const int lane = t & 63;
  const int wave = t >> 6;
  const int l16 = lane & 15;
  const int quad = lane >> 4;
  const long long row0 = (long long)blockIdx.x * TM;
  const int mrow = wave * 32;

  // stage X tile -> sA (bf16, row-major [128][LDW])
  {
    const float4* xv = reinterpret_cast<const float4*>(x + row0 * DD);
    #pragma unroll
    for (int i = 0; i < 16; ++i) {
      int v = t + 256 * i;          // 128 rows x 32 float4
      int r = v >> 5, c = v & 31;
      float4 f = xv[r * 32 + c];
      store4bf(&sA[r * LDW + c * 4], f);
    }
  }
  __syncthreads();

  const unsigned short* W1p = wbf;
  const unsigned short* W2p = wbf + 16384;
  const unsigned short* Wihp = wbf + 32768;
  const unsigned short* Whhp = wbf + 81920;

  // ---- GEMM1: h1 = elu(X @ W1^T + b1) -> sB ----
  {
    f32x4 acc[2][8];
    #pragma unroll
    for (int mi = 0; mi < 2; ++mi)
      #pragma unroll
      for (int ni = 0; ni < 8; ++ni) acc[mi][ni] = {0.f, 0.f, 0.f, 0.f};
    #pragma unroll
    for (int kk = 0; kk < 4; ++kk) {
      frag8 a0 = *reinterpret_cast<const frag8*>(&sA[(mrow + l16) * LDW + kk * 32 + quad * 8]);
      frag8 a1 = *reinterpret_cast<const frag8*>(&sA[(mrow + 16 + l16) * LDW + kk * 32 + quad * 8]);
      #pragma unroll
      for (int ni = 0; ni < 8; ++ni) {
        frag8 b = *reinterpret_cast<const frag8*>(&W1p[(ni * 16 + l16) * DD + kk * 32 + quad * 8]);
        acc[0][ni] = __builtin_amdgcn_mfma_f32_16x16x32_bf16(a0, b, acc[0][ni], 0, 0, 0);
        acc[1][ni] = __builtin_amdgcn_mfma_f32_16x16x32_bf16(a1, b, acc[1][ni], 0, 0, 0);
      }
    }
    #pragma unroll
    for (int ni = 0; ni < 8; ++ni) {
      int col = ni * 16 + l16;
      float bias = b1[col];
      #pragma unroll
      for (int mi = 0; mi < 2; ++mi)
        #pragma unroll
        for (int i = 0; i < 4; ++i) {
          float v = acc[mi][ni][i] + bias;
          v = v > 0.f ? v : expm1f(v);               // ELU(alpha=1)
          int rr = mrow + mi * 16 + quad * 4 + i;    // C/D: col=lane&15, row=quad*4+reg
          sB[rr * LDW + col] = f2bf(v);
        }
    }
  }
  __syncthreads();

  // ---- GEMM2: xf = h1 @ W2^T + b2 -> sA (overwrite X; barrier above protects) ----
  {
    f32x4 acc[2][8];
    #pragma unroll
    for (int mi = 0; mi < 2; ++mi)
      #pragma unroll
      for (int ni = 0; ni < 8; ++ni) acc[mi][ni] = {0.f, 0.f, 0.f, 0.f};
    #pragma unroll
    for (int kk = 0; kk < 4; ++kk) {
      frag8 a0 = *reinterpret_cast<const frag8*>(&sB[(mrow + l16) * LDW + kk * 32 + quad * 8]);
      frag8 a1 = *reinterpret_cast<const frag8*>(&sB[(mrow + 16 + l16) * LDW + kk * 32 + quad * 8]);
      #pragma unroll
      for (int ni = 0; ni < 8; ++ni) {
        frag8 b = *reinterpret_cast<const frag8*>(&W2p[(ni * 16 + l16) * DD + kk * 32 + quad * 8]);
        acc[0][ni] = __builtin_amdgcn_mfma_f32_16x16x32_bf16(a0, b, acc[0][ni], 0, 0, 0);
        acc[1][ni] = __builtin_amdgcn_mfma_f32_16x16x32_bf16(a1, b, acc[1][ni], 0, 0, 0);
      }
    }
    #pragma unroll
    for (int ni = 0; ni < 8; ++ni) {
      int col = ni * 16 + l16;
      float bias = b2[col];
      #pragma unroll
      for (int mi = 0; mi < 2; ++mi)
        #pragma unroll
        for (int i = 0; i < 4; ++i) {
          float v = acc[mi][ni][i] + bias;
          int rr = mrow + mi * 16 + quad * 4 + i;
          sA[rr * LDW + col] = f2bf(v);
        }
    }
  }
  __syncthreads();

  // ---- stage mem = history[T-1][idx] -> sB (bf16) and memo (f32, exact output) ----
  {
    #pragma unroll
    for (int i = 0; i < 16; ++i) {
      int v = t + 256 * i;
      int r = v >> 5, c = v & 31;
      long long ri = idx[row0 + r];
      float4 f = *reinterpret_cast<const float4*>(hist + (2 * N + ri) * DD + (long long)c * 4);
      reinterpret_cast<float4*>(memo + (row0 + r) * DD)[c] = f;
      store4bf(&sB[r * LDW + c * 4], f);
    }
  }
  __syncthreads();

  // ---- GRU: gi = xf@W_ih^T + b_ih ; gh = mem@W_hh^T + b_hh ; combine ----
  // process 16 output cols per chunk; need gate tiles at col, col+128, col+256
  #pragma unroll
  for (int nc = 0; nc < 8; ++nc) {
    f32x4 acc[6][2];  // [giR,giZ,giN,ghR,ghZ,ghN][mi]
    #pragma unroll
    for (int g = 0; g < 6; ++g)
      #pragma unroll
      for (int mi = 0; mi < 2; ++mi) acc[g][mi] = {0.f, 0.f, 0.f, 0.f};
    #pragma unroll
    for (int kk = 0; kk < 4; ++kk) {
      frag8 ax0 = *reinterpret_cast<const frag8*>(&sA[(mrow + l16) * LDW + kk * 32 + quad * 8]);
      frag8 ax1 = *reinterpret_cast<const frag8*>(&sA[(mrow + 16 + l16) * LDW + kk * 32 + quad * 8]);
      frag8 am0 = *reinterpret_cast<const frag8*>(&sB[(mrow + l16) * LDW + kk * 32 + quad * 8]);
      frag8 am1 = *reinterpret_cast<const frag8*>(&sB[(mrow + 16 + l16) * LDW + kk * 32 + quad * 8]);
      #pragma unroll
      for (int g = 0; g < 3; ++g) {
        frag8 bi = *reinterpret_cast<const frag8*>(&Wihp[(g * 128 + nc * 16 + l16) * DD + kk * 32 + quad * 8]);
        acc[g][0] = __builtin_amdgcn_mfma_f32_16x16x32_bf16(ax0, bi, acc[g][0], 0, 0, 0);
        acc[g][1] = __builtin_amdgcn_mfma_f32_16x16x32_bf16(ax1, bi, acc[g][1], 0, 0, 0);
        frag8 bh = *reinterpret_cast<const frag8*>(&Whhp[(g * 128 + nc * 16 + l16) * DD + kk * 32 + quad * 8]);
        acc[3 + g][0] = __builtin_amdgcn_mfma_f32_16x16x32_bf16(am0, bh, acc[3 + g][0], 0, 0, 0);
        acc[3 + g][1] = __builtin_amdgcn_mfma_f32_16x16x32_bf16(am1, bh, acc[3 + g][1], 0, 0, 0);
      }
    }
    int col = nc * 16 + l16;
    float br_i = bih[col], bz_i = bih[128 + col], bn_i = bih[256 + col];
    float br_h = bhh[col], bz_h = bhh[128 + col], bn_h = bhh[256 + col];
    #pragma unroll
    for (int mi = 0; mi < 2; ++mi)
      #pragma unroll
      for (int i = 0; i < 4; ++i) {
        int rr = mrow + mi * 16 + quad * 4 + i;
        float gr = acc[0][mi][i] + br_i + acc[3][mi][i] + br_h;
        float gz = acc[1][mi][i] + bz_i + acc[4][mi][i] + bz_h;
        float rg = 1.f / (1.f + __expf(-gr));
        float zg = 1.f / (1.f + __expf(-gz));
        float ng = tanhf(acc[2][mi][i] + bn_i + rg * (acc[5][mi][i] + bn_h));
        float m = bf2f(sB[rr * LDW + col]);  // mem (bf16 copy; err << threshold)
        out[(row0 + rr) * DD + col] = (1.f - zg) * ng + zg * m;
      }
  }
}

// ---- K3: fused history shift+scatter ----
// nh[0][r] = flagged ? hist[1][r] : hist[0][r]
// nh[1][r] = flagged ? hist[2][r] : hist[1][r]
// nh[2][r] = flagged ? out[winner[r]] : hist[2][r]
__global__ __launch_bounds__(256) void history_update(
    const float* __restrict__ hist, const float* __restrict__ outp,
    const int* __restrict__ winner, float* __restrict__ nh, int N) {
  long long tid = (long long)blockIdx.x * 256 + threadIdx.x;  // over N*32 float4
  long long total = (long long)N * 32;
  if (tid >= total) return;
  int s = blockIdx.y;  // slot (uniform per block)
  long long r = tid >> 5;
  int c = (int)(tid & 31);
  int w = winner[r];
  const float4* h = reinterpret_cast<const float4*>(hist);
  const float4* src;
  if (s == 0)      src = (w >= 0) ? (h + total + tid) : (h + tid);
  else if (s == 1) src = (w >= 0) ? (h + 2 * total + tid) : (h + total + tid);
  else             src = (w >= 0) ? (reinterpret_cast<const float4*>(outp) + (long long)w * 32 + c)
                                  : (h + 2 * total + tid);
  reinterpret_cast<float4*>(nh)[(long long)s * total + tid] = *src;
}

extern "C" void kernel_launch(void* const* d_in, const int* in_sizes, int n_in,
                              void* d_out, int out_size, void* d_ws, size_t ws_size,
                              hipStream_t stream) {
  const float* x   = (const float*)d_in[0];
  const int* idx   = (const int*)d_in[1];   // jnp.int64 request folds to int32 (x64 disabled)
  const float* hist= (const float*)d_in[2];
  const float* W1  = (const float*)d_in[3];
  const float* b1  = (const float*)d_in[4];
  const float* W2  = (const float*)d_in[5];
  const float* b2  = (const float*)d_in[6];
  const float* Wih = (const float*)d_in[7];
  const float* bih = (const float*)d_in[8];
  const float* Whh = (const float*)d_in[9];
  const float* bhh = (const float*)d_in[10];

  const long long Bn = in_sizes[0] / DD;            // 65536
  const long long N  = in_sizes[2] / (3LL * DD);    // 500000

  unsigned short* wbf = (unsigned short*)d_ws;                 // 262144 B
  int* winner = (int*)((char*)d_ws + 262144);                  // N*4 B

  float* out  = (float*)d_out;
  float* memo = out + Bn * DD;
  float* nh   = out + 2 * Bn * DD;

  convert_weights<<<512, 256, 0, stream>>>(W1, W2, Wih, Whh, wbf);
  init_winner<<<(int)((N + 255) / 256), 256, 0, stream>>>(winner, (int)N);
  scatter_winner<<<(int)((Bn + 255) / 256), 256, 0, stream>>>(idx, winner, (int)Bn);
  mlp_gru<<<(int)(Bn / TM), 256, 0, stream>>>(x, idx, hist, wbf, b1, b2, bih, bhh,
                                              out, memo, N);
  dim3 g3((unsigned)((N * 32 + 255) / 256), 3);
  history_update<<<g3, 256, 0, stream>>>(hist, out, winner, nh, (int)N);
}